// Round 1
// baseline (1514.749 us; speedup 1.0000x reference)
//
#include <hip/hip_runtime.h>

#define NN 100000
#define NE 1250000
#define NR 8
#define DD 64
#define TILE 128
#define NTILES 782                 // ceil(100000/128)
#define NBUCKETS (NR * NTILES)     // 6256
#define EPSB 1e-5f

// ---------------- CSR-ish bucket build (once per call) ----------------

__global__ void count_kernel(const int* __restrict__ dst,
                             const int* __restrict__ et,
                             int* __restrict__ cnt) {
    int i = blockIdx.x * 256 + threadIdx.x;
    if (i < NE) {
        atomicAdd(&cnt[et[i] * NTILES + (dst[i] >> 7)], 1);
    }
}

__global__ void scan_kernel(const int* __restrict__ cnt, int* __restrict__ off) {
    __shared__ int ts[1024];
    int t = threadIdx.x;
    int v[8];
    int s = 0;
#pragma unroll
    for (int j = 0; j < 8; j++) {
        int idx = t * 8 + j;
        int c = (idx < NBUCKETS) ? cnt[idx] : 0;
        v[j] = s;
        s += c;
    }
    ts[t] = s;
    __syncthreads();
    for (int d = 1; d < 1024; d <<= 1) {
        int add = (t >= d) ? ts[t - d] : 0;
        __syncthreads();
        ts[t] += add;
        __syncthreads();
    }
    int base = (t > 0) ? ts[t - 1] : 0;
#pragma unroll
    for (int j = 0; j < 8; j++) {
        int idx = t * 8 + j;
        if (idx < NBUCKETS) off[idx] = base + v[j];
    }
    if (t == 1023) off[NBUCKETS] = ts[1023];
}

__global__ void fill_kernel(const int* __restrict__ src, const int* __restrict__ dst,
                            const int* __restrict__ et, const int* __restrict__ off,
                            int* __restrict__ cursor, int* __restrict__ ep) {
    int i = blockIdx.x * 256 + threadIdx.x;
    if (i < NE) {
        int d = dst[i];
        int b = et[i] * NTILES + (d >> 7);
        int pos = off[b] + atomicAdd(&cursor[b], 1);
        ep[pos] = (src[i] << 7) | (d & 127);
    }
}

// ---------------- GEMM1: LDS-gather (or root copy) -> z = h@W1 + b1, + BN stats ----------------

__launch_bounds__(256, 3)
__global__ void gemm1_kernel(const float* __restrict__ x,
                             const int* __restrict__ ep, const int* __restrict__ off,
                             const float* __restrict__ W1l, const float* __restrict__ b1l,
                             const float* __restrict__ rW1l, const float* __restrict__ rb1l,
                             float* __restrict__ z, float* __restrict__ stats) {
    __shared__ __align__(16) float hs[TILE][68];   // stride 68: conflict-free b128
    __shared__ __align__(16) float Ws[DD][DD];
    __shared__ float red[2 * DD];
    int r = blockIdx.y;
    int n0 = blockIdx.x * TILE;
    int tid = threadIdx.x;

    const float* W = (r < NR) ? (W1l + (size_t)r * DD * DD) : rW1l;
    for (int idx = tid; idx < DD * DD; idx += 256)
        ((float*)Ws)[idx] = W[idx];

    if (r < NR) {
        for (int idx = tid; idx < TILE * 68; idx += 256)
            ((float*)hs)[idx] = 0.f;
        __syncthreads();
        int b = r * NTILES + blockIdx.x;
        int e0 = off[b], e1 = off[b + 1];
        int lane = tid & 63;
        for (int e = e0 + (tid >> 6); e < e1; e += 4) {
            int p = ep[e];
            float v = x[(size_t)(p >> 7) * DD + lane];
            atomicAdd(&hs[p & 127][lane], v);  // ds_add_f32, no return
        }
    } else {
        for (int idx = tid; idx < TILE * 16; idx += 256) {
            int nn = idx >> 4, kq = (idx & 15) * 4;
            int n = n0 + nn;
            float4 vv = make_float4(0.f, 0.f, 0.f, 0.f);
            if (n < NN) vv = *(const float4*)&x[(size_t)n * DD + kq];
            *(float4*)&hs[nn][kq] = vv;
        }
    }
    __syncthreads();

    int tn = tid >> 3;          // 0..31
    int d0 = (tid & 7) * 8;

    float acc[4][8];
#pragma unroll
    for (int j = 0; j < 4; j++)
#pragma unroll
        for (int m = 0; m < 8; m++) acc[j][m] = 0.f;

#pragma unroll 4
    for (int kk = 0; kk < DD; kk += 4) {
        float hreg[4][4];
#pragma unroll
        for (int j = 0; j < 4; j++) {
            float4 t4 = *(const float4*)&hs[tn + 32 * j][kk];
            hreg[j][0] = t4.x; hreg[j][1] = t4.y; hreg[j][2] = t4.z; hreg[j][3] = t4.w;
        }
#pragma unroll
        for (int c = 0; c < 4; c++) {
            float4 wa = *(const float4*)&Ws[kk + c][d0];
            float4 wb = *(const float4*)&Ws[kk + c][d0 + 4];
            float w8[8] = {wa.x, wa.y, wa.z, wa.w, wb.x, wb.y, wb.z, wb.w};
#pragma unroll
            for (int j = 0; j < 4; j++)
#pragma unroll
                for (int m = 0; m < 8; m++)
                    acc[j][m] = fmaf(hreg[j][c], w8[m], acc[j][m]);
        }
    }

    const float* bvec = (r < NR) ? (b1l + r * DD) : rb1l;
    float bv[8];
#pragma unroll
    for (int m = 0; m < 8; m++) bv[m] = bvec[d0 + m];

    float* zout = z + (size_t)r * NN * DD;
    float s1[8], s2[8];
#pragma unroll
    for (int m = 0; m < 8; m++) { s1[m] = 0.f; s2[m] = 0.f; }

#pragma unroll
    for (int j = 0; j < 4; j++) {
        int n = n0 + tn + 32 * j;
        if (n < NN) {
            float vv[8];
#pragma unroll
            for (int m = 0; m < 8; m++) {
                float v = acc[j][m] + bv[m];
                vv[m] = v;
                s1[m] += v;
                s2[m] += v * v;
            }
            *(float4*)&zout[(size_t)n * DD + d0]     = make_float4(vv[0], vv[1], vv[2], vv[3]);
            *(float4*)&zout[(size_t)n * DD + d0 + 4] = make_float4(vv[4], vv[5], vv[6], vv[7]);
        }
    }

    // block-level stats reduction: wave shuffle (same td group) -> LDS -> global
    if (tid < 128) red[tid] = 0.f;
    __syncthreads();
#pragma unroll
    for (int m = 0; m < 8; m++) {
        float a = s1[m], bq = s2[m];
        a += __shfl_xor(a, 8);  bq += __shfl_xor(bq, 8);
        a += __shfl_xor(a, 16); bq += __shfl_xor(bq, 16);
        a += __shfl_xor(a, 32); bq += __shfl_xor(bq, 32);
        if ((tid & 63) < 8) {
            atomicAdd(&red[d0 + m], a);
            atomicAdd(&red[64 + d0 + m], bq);
        }
    }
    __syncthreads();
    if (tid < 64) {
        atomicAdd(&stats[r * DD + tid], red[tid]);
        atomicAdd(&stats[576 + r * DD + tid], red[64 + tid]);
    }
}

// ---------------- finalize: BN affine + fused const bias ----------------

__global__ void finalize_kernel(const float* __restrict__ stats,
                                const float* __restrict__ g1l, const float* __restrict__ be1l,
                                const float* __restrict__ rg1l, const float* __restrict__ rbe1l,
                                const float* __restrict__ b2l, const float* __restrict__ rb2l,
                                const float* __restrict__ biasl,
                                float* __restrict__ affine, float* __restrict__ constd) {
    int t = threadIdx.x;
    if (t < 576) {
        int r = t >> 6, d = t & 63;
        float mean = stats[t] * (1.f / NN);
        float var = fmaxf(stats[576 + t] * (1.f / NN) - mean * mean, 0.f);
        float g  = (r < NR) ? g1l[r * DD + d]  : rg1l[d];
        float be = (r < NR) ? be1l[r * DD + d] : rbe1l[d];
        float sc = g * rsqrtf(var + EPSB);
        affine[t] = sc;
        affine[576 + t] = be - mean * sc;
        if (r == 0) {
            float cd = rb2l[d] + biasl[d];
#pragma unroll
            for (int rr = 0; rr < NR; rr++) cd += b2l[rr * DD + d];
            constd[d] = cd;
        }
    }
}

// ---------------- pass2: out = sum_r relu(bn(z_r)) @ W2_r + const, optional relu ----------------

__launch_bounds__(256, 3)
__global__ void pass2_kernel(const float* __restrict__ z,
                             const float* __restrict__ W2l, const float* __restrict__ rW2l,
                             const float* __restrict__ affine, const float* __restrict__ constd,
                             float* __restrict__ out, int do_relu) {
    __shared__ __align__(16) float zs[TILE][68];
    __shared__ __align__(16) float W2s[DD][DD];
    int n0 = blockIdx.x * TILE;
    int tid = threadIdx.x;
    int tn = tid >> 3;
    int d0 = (tid & 7) * 8;

    float acc[4][8];
#pragma unroll
    for (int j = 0; j < 4; j++)
#pragma unroll
        for (int m = 0; m < 8; m++) acc[j][m] = 0.f;

    for (int r = 0; r < 9; r++) {
        __syncthreads();   // previous iteration's compute done before restaging
        const float* W = (r < NR) ? (W2l + (size_t)r * DD * DD) : rW2l;
        for (int idx = tid; idx < DD * DD; idx += 256)
            ((float*)W2s)[idx] = W[idx];
        const float* zsl = z + (size_t)r * NN * DD;
        const float* av = affine + r * DD;
        const float* cv = affine + 576 + r * DD;
        for (int idx = tid; idx < TILE * 16; idx += 256) {
            int nn = idx >> 4, kq = (idx & 15) * 4;
            int n = n0 + nn;
            float4 vv = make_float4(0.f, 0.f, 0.f, 0.f);
            if (n < NN) vv = *(const float4*)&zsl[(size_t)n * DD + kq];
            float4 a4 = *(const float4*)&av[kq];
            float4 c4 = *(const float4*)&cv[kq];
            vv.x = fmaxf(fmaf(vv.x, a4.x, c4.x), 0.f);
            vv.y = fmaxf(fmaf(vv.y, a4.y, c4.y), 0.f);
            vv.z = fmaxf(fmaf(vv.z, a4.z, c4.z), 0.f);
            vv.w = fmaxf(fmaf(vv.w, a4.w, c4.w), 0.f);
            *(float4*)&zs[nn][kq] = vv;
        }
        __syncthreads();

#pragma unroll 4
        for (int kk = 0; kk < DD; kk += 4) {
            float hreg[4][4];
#pragma unroll
            for (int j = 0; j < 4; j++) {
                float4 t4 = *(const float4*)&zs[tn + 32 * j][kk];
                hreg[j][0] = t4.x; hreg[j][1] = t4.y; hreg[j][2] = t4.z; hreg[j][3] = t4.w;
            }
#pragma unroll
            for (int c = 0; c < 4; c++) {
                float4 wa = *(const float4*)&W2s[kk + c][d0];
                float4 wb = *(const float4*)&W2s[kk + c][d0 + 4];
                float w8[8] = {wa.x, wa.y, wa.z, wa.w, wb.x, wb.y, wb.z, wb.w};
#pragma unroll
                for (int j = 0; j < 4; j++)
#pragma unroll
                    for (int m = 0; m < 8; m++)
                        acc[j][m] = fmaf(hreg[j][c], w8[m], acc[j][m]);
            }
        }
    }

    float cd[8];
#pragma unroll
    for (int m = 0; m < 8; m++) cd[m] = constd[d0 + m];

#pragma unroll
    for (int j = 0; j < 4; j++) {
        int n = n0 + tn + 32 * j;
        if (n < NN) {
            float vv[8];
#pragma unroll
            for (int m = 0; m < 8; m++) {
                float v = acc[j][m] + cd[m];
                if (do_relu) v = fmaxf(v, 0.f);
                vv[m] = v;
            }
            *(float4*)&out[(size_t)n * DD + d0]     = make_float4(vv[0], vv[1], vv[2], vv[3]);
            *(float4*)&out[(size_t)n * DD + d0 + 4] = make_float4(vv[4], vv[5], vv[6], vv[7]);
        }
    }
}

// ---------------- host ----------------

extern "C" void kernel_launch(void* const* d_in, const int* in_sizes, int n_in,
                              void* d_out, int out_size, void* d_ws, size_t ws_size,
                              hipStream_t stream) {
    (void)in_sizes; (void)n_in; (void)out_size;

    const float* x0   = (const float*)d_in[0];
    const int*   ei   = (const int*)d_in[1];
    const int*   et   = (const int*)d_in[2];
    const float* W1   = (const float*)d_in[3];
    const float* b1   = (const float*)d_in[4];
    const float* g1   = (const float*)d_in[5];
    const float* be1  = (const float*)d_in[6];
    const float* W2   = (const float*)d_in[7];
    const float* b2   = (const float*)d_in[8];
    const float* rW1  = (const float*)d_in[9];
    const float* rb1  = (const float*)d_in[10];
    const float* rg1  = (const float*)d_in[11];
    const float* rbe1 = (const float*)d_in[12];
    const float* rW2  = (const float*)d_in[13];
    const float* rb2  = (const float*)d_in[14];
    const float* bias = (const float*)d_in[15];
    float* out = (float*)d_out;

    char* ws = (char*)d_ws;
    size_t zfloats = (size_t)9 * NN * DD;
    float* z      = (float*)ws;
    float* stats  = z + zfloats;           // 1152 floats (sum | sumsq)
    float* affine = stats + 1152;          // 1152 floats (a | c)
    float* constd = affine + 1152;         // 64 floats
    int*   cnt    = (int*)(constd + 64);   // NBUCKETS
    int*   cursor = cnt + NBUCKETS;        // NBUCKETS
    int*   off    = cursor + NBUCKETS;     // NBUCKETS+1
    int*   ep     = off + NBUCKETS + 1;    // NE

    size_t need = (zfloats + 1152 + 1152 + 64) * 4
                + (size_t)(2 * NBUCKETS + NBUCKETS + 1 + NE) * 4;
    if (ws_size < need) return;  // insufficient scratch: bail (will fail validation visibly)

    hipMemsetAsync(cnt, 0, sizeof(int) * 2 * NBUCKETS, stream);
    count_kernel<<<(NE + 255) / 256, 256, 0, stream>>>(ei + NE, et, cnt);
    scan_kernel<<<1, 1024, 0, stream>>>(cnt, off);
    fill_kernel<<<(NE + 255) / 256, 256, 0, stream>>>(ei, ei + NE, et, off, cursor, ep);

    for (int i = 0; i < 2; i++) {
        const float* xi = (i == 0) ? x0 : out;
        hipMemsetAsync(stats, 0, sizeof(float) * 1152, stream);
        gemm1_kernel<<<dim3(NTILES, 9), 256, 0, stream>>>(
            xi, ep, off,
            W1 + (size_t)i * NR * DD * DD, b1 + (size_t)i * NR * DD,
            rW1 + (size_t)i * DD * DD, rb1 + (size_t)i * DD,
            z, stats);
        finalize_kernel<<<1, 576, 0, stream>>>(
            stats,
            g1 + (size_t)i * NR * DD, be1 + (size_t)i * NR * DD,
            rg1 + (size_t)i * DD, rbe1 + (size_t)i * DD,
            b2 + (size_t)i * NR * DD, rb2 + (size_t)i * DD, bias + (size_t)i * DD,
            affine, constd);
        pass2_kernel<<<NTILES, 256, 0, stream>>>(
            z, W2 + (size_t)i * NR * DD * DD, rW2 + (size_t)i * DD * DD,
            affine, constd, out, (i == 0) ? 1 : 0);
    }
}

// Round 2
// 1430.595 us; speedup vs baseline: 1.0588x; 1.0588x over previous
//
#include <hip/hip_runtime.h>

#define NN 100000
#define NE 1250000
#define NR 8
#define DD 64
#define TILE 128
#define NTILES 782                 // ceil(100000/128)
#define NBUCKETS (NR * NTILES)     // 6256
#define EPSB 1e-5f

// ---------------- CSR-ish bucket build (once per call) ----------------

__global__ void count_kernel(const int* __restrict__ dst,
                             const int* __restrict__ et,
                             int* __restrict__ cnt) {
    int i = blockIdx.x * 256 + threadIdx.x;
    if (i < NE) {
        atomicAdd(&cnt[et[i] * NTILES + (dst[i] >> 7)], 1);
    }
}

__global__ void scan_kernel(const int* __restrict__ cnt, int* __restrict__ off) {
    __shared__ int ts[1024];
    int t = threadIdx.x;
    int v[8];
    int s = 0;
#pragma unroll
    for (int j = 0; j < 8; j++) {
        int idx = t * 8 + j;
        int c = (idx < NBUCKETS) ? cnt[idx] : 0;
        v[j] = s;
        s += c;
    }
    ts[t] = s;
    __syncthreads();
    for (int d = 1; d < 1024; d <<= 1) {
        int add = (t >= d) ? ts[t - d] : 0;
        __syncthreads();
        ts[t] += add;
        __syncthreads();
    }
    int base = (t > 0) ? ts[t - 1] : 0;
#pragma unroll
    for (int j = 0; j < 8; j++) {
        int idx = t * 8 + j;
        if (idx < NBUCKETS) off[idx] = base + v[j];
    }
    if (t == 1023) off[NBUCKETS] = ts[1023];
}

__global__ void fill_kernel(const int* __restrict__ src, const int* __restrict__ dst,
                            const int* __restrict__ et, const int* __restrict__ off,
                            int* __restrict__ cursor, int* __restrict__ ep) {
    int i = blockIdx.x * 256 + threadIdx.x;
    if (i < NE) {
        int d = dst[i];
        int b = et[i] * NTILES + (d >> 7);
        int pos = off[b] + atomicAdd(&cursor[b], 1);
        ep[pos] = (src[i] << 7) | (d & 127);
    }
}

// ---------------- GEMM1: LDS-gather (or root copy) -> z = h@W1 + b1, + BN stats ----------------

__launch_bounds__(256, 3)
__global__ void gemm1_kernel(const float* __restrict__ x,
                             const int* __restrict__ ep, const int* __restrict__ off,
                             const float* __restrict__ W1l, const float* __restrict__ b1l,
                             const float* __restrict__ rW1l, const float* __restrict__ rb1l,
                             float* __restrict__ z, float* __restrict__ stats) {
    __shared__ __align__(16) float hs[TILE][68];   // stride 68: conflict-free b128
    __shared__ __align__(16) float Ws[DD][DD];
    __shared__ float red[2 * DD];
    int r = blockIdx.y;
    int n0 = blockIdx.x * TILE;
    int tid = threadIdx.x;

    const float* W = (r < NR) ? (W1l + (size_t)r * DD * DD) : rW1l;
    for (int idx = tid; idx < DD * DD; idx += 256)
        ((float*)Ws)[idx] = W[idx];

    if (r < NR) {
        for (int idx = tid; idx < TILE * 68; idx += 256)
            ((float*)hs)[idx] = 0.f;
        __syncthreads();
        int b = r * NTILES + blockIdx.x;
        int e0 = off[b], e1 = off[b + 1];
        int sub = tid >> 5;        // 0..7: which edge slot within a group of 8
        int l2 = tid & 31;         // 32 lanes x float2 cover one 64-float row
        for (int e = e0 + sub; e < e1; e += 32) {
            int p[4];
            float2 v[4];
#pragma unroll
            for (int j = 0; j < 4; j++) {
                int ee = e + 8 * j;
                p[j] = (ee < e1) ? ep[ee] : -1;
            }
#pragma unroll
            for (int j = 0; j < 4; j++)
                if (p[j] >= 0)
                    v[j] = *(const float2*)&x[(size_t)(p[j] >> 7) * DD + l2 * 2];
#pragma unroll
            for (int j = 0; j < 4; j++)
                if (p[j] >= 0) {
                    atomicAdd(&hs[p[j] & 127][l2 * 2], v[j].x);
                    atomicAdd(&hs[p[j] & 127][l2 * 2 + 1], v[j].y);
                }
        }
    } else {
        for (int idx = tid; idx < TILE * 16; idx += 256) {
            int nn = idx >> 4, kq = (idx & 15) * 4;
            int n = n0 + nn;
            float4 vv = make_float4(0.f, 0.f, 0.f, 0.f);
            if (n < NN) vv = *(const float4*)&x[(size_t)n * DD + kq];
            *(float4*)&hs[nn][kq] = vv;
        }
    }
    __syncthreads();

    int tn = tid >> 3;          // 0..31
    int d0 = (tid & 7) * 8;

    float acc[4][8];
#pragma unroll
    for (int j = 0; j < 4; j++)
#pragma unroll
        for (int m = 0; m < 8; m++) acc[j][m] = 0.f;

#pragma unroll 4
    for (int kk = 0; kk < DD; kk += 4) {
        float hreg[4][4];
#pragma unroll
        for (int j = 0; j < 4; j++) {
            float4 t4 = *(const float4*)&hs[tn + 32 * j][kk];
            hreg[j][0] = t4.x; hreg[j][1] = t4.y; hreg[j][2] = t4.z; hreg[j][3] = t4.w;
        }
#pragma unroll
        for (int c = 0; c < 4; c++) {
            float4 wa = *(const float4*)&Ws[kk + c][d0];
            float4 wb = *(const float4*)&Ws[kk + c][d0 + 4];
            float w8[8] = {wa.x, wa.y, wa.z, wa.w, wb.x, wb.y, wb.z, wb.w};
#pragma unroll
            for (int j = 0; j < 4; j++)
#pragma unroll
                for (int m = 0; m < 8; m++)
                    acc[j][m] = fmaf(hreg[j][c], w8[m], acc[j][m]);
        }
    }

    const float* bvec = (r < NR) ? (b1l + r * DD) : rb1l;
    float bv[8];
#pragma unroll
    for (int m = 0; m < 8; m++) bv[m] = bvec[d0 + m];

    float* zout = z + (size_t)r * NN * DD;
    float s1[8], s2[8];
#pragma unroll
    for (int m = 0; m < 8; m++) { s1[m] = 0.f; s2[m] = 0.f; }

#pragma unroll
    for (int j = 0; j < 4; j++) {
        int n = n0 + tn + 32 * j;
        if (n < NN) {
            float vv[8];
#pragma unroll
            for (int m = 0; m < 8; m++) {
                float v = acc[j][m] + bv[m];
                vv[m] = v;
                s1[m] += v;
                s2[m] += v * v;
            }
            *(float4*)&zout[(size_t)n * DD + d0]     = make_float4(vv[0], vv[1], vv[2], vv[3]);
            *(float4*)&zout[(size_t)n * DD + d0 + 4] = make_float4(vv[4], vv[5], vv[6], vv[7]);
        }
    }

    // block-level stats reduction: wave shuffle (same d0 group) -> LDS -> global
    if (tid < 128) red[tid] = 0.f;
    __syncthreads();
#pragma unroll
    for (int m = 0; m < 8; m++) {
        float a = s1[m], bq = s2[m];
        a += __shfl_xor(a, 8);  bq += __shfl_xor(bq, 8);
        a += __shfl_xor(a, 16); bq += __shfl_xor(bq, 16);
        a += __shfl_xor(a, 32); bq += __shfl_xor(bq, 32);
        if ((tid & 63) < 8) {
            atomicAdd(&red[d0 + m], a);
            atomicAdd(&red[64 + d0 + m], bq);
        }
    }
    __syncthreads();
    if (tid < 64) {
        atomicAdd(&stats[r * DD + tid], red[tid]);
        atomicAdd(&stats[576 + r * DD + tid], red[64 + tid]);
    }
}

// ---------------- finalize: BN affine + fused const bias ----------------

__global__ void finalize_kernel(const float* __restrict__ stats,
                                const float* __restrict__ g1l, const float* __restrict__ be1l,
                                const float* __restrict__ rg1l, const float* __restrict__ rbe1l,
                                const float* __restrict__ b2l, const float* __restrict__ rb2l,
                                const float* __restrict__ biasl,
                                float* __restrict__ affine, float* __restrict__ constd) {
    int t = threadIdx.x;
    if (t < 576) {
        int r = t >> 6, d = t & 63;
        float mean = stats[t] * (1.f / NN);
        float var = fmaxf(stats[576 + t] * (1.f / NN) - mean * mean, 0.f);
        float g  = (r < NR) ? g1l[r * DD + d]  : rg1l[d];
        float be = (r < NR) ? be1l[r * DD + d] : rbe1l[d];
        float sc = g * rsqrtf(var + EPSB);
        affine[t] = sc;
        affine[576 + t] = be - mean * sc;
        if (r == 0) {
            float cd = rb2l[d] + biasl[d];
#pragma unroll
            for (int rr = 0; rr < NR; rr++) cd += b2l[rr * DD + d];
            constd[d] = cd;
        }
    }
}

// ---------------- pass2: out = sum_r relu(bn(z_r)) @ W2_r + const, optional relu ----------------

__launch_bounds__(256, 3)
__global__ void pass2_kernel(const float* __restrict__ z,
                             const float* __restrict__ W2l, const float* __restrict__ rW2l,
                             const float* __restrict__ affine, const float* __restrict__ constd,
                             float* __restrict__ out, int do_relu) {
    __shared__ __align__(16) float zs[TILE][68];
    __shared__ __align__(16) float W2s[DD][DD];
    int n0 = blockIdx.x * TILE;
    int tid = threadIdx.x;
    int tn = tid >> 3;
    int d0 = (tid & 7) * 8;
    int kq = (tid & 15) * 4;   // staging column (fixed per thread)
    int nnb = tid >> 4;        // staging row base (0..15)

    float acc[4][8];
#pragma unroll
    for (int j = 0; j < 4; j++)
#pragma unroll
        for (int m = 0; m < 8; m++) acc[j][m] = 0.f;

    float4 pre[8];
    // prologue: issue loads for r=0 tile
    {
        const float* zp = z;
#pragma unroll
        for (int k = 0; k < 8; k++) {
            int n = n0 + nnb + 16 * k;
            pre[k] = (n < NN) ? *(const float4*)&zp[(size_t)n * DD + kq]
                              : make_float4(0.f, 0.f, 0.f, 0.f);
        }
    }

    for (int r = 0; r < 9; r++) {
        float4 a4 = *(const float4*)&affine[r * DD + kq];
        float4 c4 = *(const float4*)&affine[576 + r * DD + kq];
        __syncthreads();   // previous iteration's GEMM done reading zs
        // write prefetched tile with BN affine + ReLU
#pragma unroll
        for (int k = 0; k < 8; k++) {
            float4 vv = pre[k];
            vv.x = fmaxf(fmaf(vv.x, a4.x, c4.x), 0.f);
            vv.y = fmaxf(fmaf(vv.y, a4.y, c4.y), 0.f);
            vv.z = fmaxf(fmaf(vv.z, a4.z, c4.z), 0.f);
            vv.w = fmaxf(fmaf(vv.w, a4.w, c4.w), 0.f);
            *(float4*)&zs[nnb + 16 * k][kq] = vv;
        }
        // stage W2 (L2-hot: all blocks read the same 16 KB)
        const float* W = (r < NR) ? (W2l + (size_t)r * DD * DD) : rW2l;
        for (int idx = tid; idx < DD * DD; idx += 256)
            ((float*)W2s)[idx] = W[idx];
        __syncthreads();
        // issue next relation's z loads NOW; they fly during the GEMM below
        if (r + 1 < 9) {
            const float* zp = z + (size_t)(r + 1) * NN * DD;
#pragma unroll
            for (int k = 0; k < 8; k++) {
                int n = n0 + nnb + 16 * k;
                pre[k] = (n < NN) ? *(const float4*)&zp[(size_t)n * DD + kq]
                                  : make_float4(0.f, 0.f, 0.f, 0.f);
            }
        }

#pragma unroll 4
        for (int kk = 0; kk < DD; kk += 4) {
            float hreg[4][4];
#pragma unroll
            for (int j = 0; j < 4; j++) {
                float4 t4 = *(const float4*)&zs[tn + 32 * j][kk];
                hreg[j][0] = t4.x; hreg[j][1] = t4.y; hreg[j][2] = t4.z; hreg[j][3] = t4.w;
            }
#pragma unroll
            for (int c = 0; c < 4; c++) {
                float4 wa = *(const float4*)&W2s[kk + c][d0];
                float4 wb = *(const float4*)&W2s[kk + c][d0 + 4];
                float w8[8] = {wa.x, wa.y, wa.z, wa.w, wb.x, wb.y, wb.z, wb.w};
#pragma unroll
                for (int j = 0; j < 4; j++)
#pragma unroll
                    for (int m = 0; m < 8; m++)
                        acc[j][m] = fmaf(hreg[j][c], w8[m], acc[j][m]);
            }
        }
    }

    float cd[8];
#pragma unroll
    for (int m = 0; m < 8; m++) cd[m] = constd[d0 + m];

#pragma unroll
    for (int j = 0; j < 4; j++) {
        int n = n0 + tn + 32 * j;
        if (n < NN) {
            float vv[8];
#pragma unroll
            for (int m = 0; m < 8; m++) {
                float v = acc[j][m] + cd[m];
                if (do_relu) v = fmaxf(v, 0.f);
                vv[m] = v;
            }
            *(float4*)&out[(size_t)n * DD + d0]     = make_float4(vv[0], vv[1], vv[2], vv[3]);
            *(float4*)&out[(size_t)n * DD + d0 + 4] = make_float4(vv[4], vv[5], vv[6], vv[7]);
        }
    }
}

// ---------------- host ----------------

extern "C" void kernel_launch(void* const* d_in, const int* in_sizes, int n_in,
                              void* d_out, int out_size, void* d_ws, size_t ws_size,
                              hipStream_t stream) {
    (void)in_sizes; (void)n_in; (void)out_size;

    const float* x0   = (const float*)d_in[0];
    const int*   ei   = (const int*)d_in[1];
    const int*   et   = (const int*)d_in[2];
    const float* W1   = (const float*)d_in[3];
    const float* b1   = (const float*)d_in[4];
    const float* g1   = (const float*)d_in[5];
    const float* be1  = (const float*)d_in[6];
    const float* W2   = (const float*)d_in[7];
    const float* b2   = (const float*)d_in[8];
    const float* rW1  = (const float*)d_in[9];
    const float* rb1  = (const float*)d_in[10];
    const float* rg1  = (const float*)d_in[11];
    const float* rbe1 = (const float*)d_in[12];
    const float* rW2  = (const float*)d_in[13];
    const float* rb2  = (const float*)d_in[14];
    const float* bias = (const float*)d_in[15];
    float* out = (float*)d_out;

    char* ws = (char*)d_ws;
    size_t zfloats = (size_t)9 * NN * DD;
    float* z      = (float*)ws;
    float* stats  = z + zfloats;           // 1152 floats (sum | sumsq)
    float* affine = stats + 1152;          // 1152 floats (a | c)
    float* constd = affine + 1152;         // 64 floats
    int*   cnt    = (int*)(constd + 64);   // NBUCKETS
    int*   cursor = cnt + NBUCKETS;        // NBUCKETS
    int*   off    = cursor + NBUCKETS;     // NBUCKETS+1
    int*   ep     = off + NBUCKETS + 1;    // NE

    size_t need = (zfloats + 1152 + 1152 + 64) * 4
                + (size_t)(2 * NBUCKETS + NBUCKETS + 1 + NE) * 4;
    if (ws_size < need) return;

    hipMemsetAsync(cnt, 0, sizeof(int) * 2 * NBUCKETS, stream);
    count_kernel<<<(NE + 255) / 256, 256, 0, stream>>>(ei + NE, et, cnt);
    scan_kernel<<<1, 1024, 0, stream>>>(cnt, off);
    fill_kernel<<<(NE + 255) / 256, 256, 0, stream>>>(ei, ei + NE, et, off, cursor, ep);

    for (int i = 0; i < 2; i++) {
        const float* xi = (i == 0) ? x0 : out;
        hipMemsetAsync(stats, 0, sizeof(float) * 1152, stream);
        gemm1_kernel<<<dim3(NTILES, 9), 256, 0, stream>>>(
            xi, ep, off,
            W1 + (size_t)i * NR * DD * DD, b1 + (size_t)i * NR * DD,
            rW1 + (size_t)i * DD * DD, rb1 + (size_t)i * DD,
            z, stats);
        finalize_kernel<<<1, 576, 0, stream>>>(
            stats,
            g1 + (size_t)i * NR * DD, be1 + (size_t)i * NR * DD,
            rg1 + (size_t)i * DD, rbe1 + (size_t)i * DD,
            b2 + (size_t)i * NR * DD, rb2 + (size_t)i * DD, bias + (size_t)i * DD,
            affine, constd);
        pass2_kernel<<<NTILES, 256, 0, stream>>>(
            z, W2 + (size_t)i * NR * DD * DD, rW2 + (size_t)i * DD * DD,
            affine, constd, out, (i == 0) ? 1 : 0);
    }
}